// Round 9
// baseline (804.873 us; speedup 1.0000x reference)
//
#include <hip/hip_runtime.h>
#include <hip/hip_bf16.h>

#define NNODES 50000
#define NEDGES 600000
#define NGRAPHS 128
#define EMB 128
#define NLAYERS 5
#define BN_EPS 1e-5f
#define SCAN_BLOCKS ((NNODES + 255) / 256)  // 196

typedef short s16x8 __attribute__((ext_vector_type(8)));
typedef float f32x4 __attribute__((ext_vector_type(4)));
typedef float f32x16 __attribute__((ext_vector_type(16)));

__device__ __forceinline__ short f2bf(float f) {
    unsigned u = __builtin_bit_cast(unsigned, f);
    unsigned r = (u + 0x7fffu + ((u >> 16) & 1u)) >> 16;  // RNE
    return (short)r;
}
__device__ __forceinline__ float bf2f(short s) {
    return __builtin_bit_cast(float, ((unsigned)(unsigned short)s) << 16);
}

// ---------------- deg histogram (int atomics only) ---------------------------
__global__ __launch_bounds__(256) void deg_kernel(const int* __restrict__ ei,
                                                  int* __restrict__ deg) {
    int e = blockIdx.x * 256 + threadIdx.x;
    if (e >= NEDGES) return;
    atomicAdd(&deg[ei[NEDGES + e]], 1);
}

// ---------------- multi-block scan ------------------------------------------
__global__ __launch_bounds__(256) void scan1(const int* __restrict__ deg,
                                             int* __restrict__ local_excl,
                                             int* __restrict__ part) {
    __shared__ int sh[256];
    int t = threadIdx.x;
    int i = blockIdx.x * 256 + t;
    int v = (i < NNODES) ? deg[i] : 0;
    sh[t] = v;
    __syncthreads();
    for (int off = 1; off < 256; off <<= 1) {
        int u = (t >= off) ? sh[t - off] : 0;
        __syncthreads();
        sh[t] += u;
        __syncthreads();
    }
    if (i < NNODES) local_excl[i] = sh[t] - v;
    if (t == 255) part[blockIdx.x] = sh[255];
}

__global__ __launch_bounds__(256) void scan2(int* __restrict__ part,
                                             int* __restrict__ blockoff,
                                             int* __restrict__ rowptr) {
    __shared__ int sh[256];
    int t = threadIdx.x;
    int v = (t < SCAN_BLOCKS) ? part[t] : 0;
    sh[t] = v;
    __syncthreads();
    for (int off = 1; off < 256; off <<= 1) {
        int u = (t >= off) ? sh[t - off] : 0;
        __syncthreads();
        sh[t] += u;
        __syncthreads();
    }
    if (t < SCAN_BLOCKS) blockoff[t] = sh[t] - v;
    if (t == 255) rowptr[NNODES] = sh[255];
}

__global__ __launch_bounds__(256) void scan3(const int* __restrict__ local_excl,
                                             const int* __restrict__ blockoff,
                                             int* __restrict__ rowptr,
                                             int* __restrict__ cursor) {
    int i = blockIdx.x * 256 + threadIdx.x;
    if (i >= NNODES) return;
    int v = local_excl[i] + blockoff[blockIdx.x];
    rowptr[i] = v;
    cursor[i] = v;
}

// ---------------- fill CSR: 32B record {src, w, 11x bf16 attr, pad} ----------
__global__ __launch_bounds__(256) void edge_fill(const int* __restrict__ ei,
                                                 const float* __restrict__ ew,
                                                 const float* __restrict__ eattr,
                                                 int* __restrict__ cursor,
                                                 int* __restrict__ epk) {
    int e = blockIdx.x * 256 + threadIdx.x;
    if (e >= NEDGES) return;
    int src = ei[e];
    int dst = ei[NEDGES + e];
    int pos = atomicAdd(&cursor[dst], 1);
    int pk[8];
    pk[0] = src;
    pk[1] = __float_as_int(ew[e]);
    unsigned short a[12];
#pragma unroll
    for (int j = 0; j < 11; j++) a[j] = (unsigned short)f2bf(eattr[e * 11 + j]);
    a[11] = 0;
#pragma unroll
    for (int j = 0; j < 6; j++)
        pk[2 + j] = (int)a[2 * j] | ((int)a[2 * j + 1] << 16);
    int* dstp = epk + (size_t)pos * 8;
    *(int4*)dstp = *(int4*)pk;
    *(int4*)(dstp + 4) = *(int4*)(pk + 4);
}

// ---------------- S[n,11], wsum[n]: sequential CSR scan, thread-per-node -----
__global__ __launch_bounds__(256) void node_S(const int* __restrict__ rowptr,
                                              const int* __restrict__ epk,
                                              float* __restrict__ S,
                                              float* __restrict__ wsum) {
    int node = blockIdx.x * 256 + threadIdx.x;
    if (node >= NNODES) return;
    int b = rowptr[node], e = rowptr[node + 1];
    float s[11];
#pragma unroll
    for (int j = 0; j < 11; j++) s[j] = 0.f;
    float ws = 0.f;
    for (int p = b; p < e; p++) {
        const int* pk = epk + (size_t)p * 8;
        int4 lo = *(const int4*)pk;
        int4 hi = *(const int4*)(pk + 4);
        float w = __int_as_float(lo.y);
        ws += w;
        int packed[6] = {lo.z, lo.w, hi.x, hi.y, hi.z, hi.w};
#pragma unroll
        for (int j = 0; j < 11; j++) {
            short v = (short)((packed[j >> 1] >> ((j & 1) * 16)) & 0xffff);
            s[j] += bf2f(v) * w;
        }
    }
#pragma unroll
    for (int j = 0; j < 11; j++) S[node * 11 + j] = s[j];
    wsum[node] = ws;
}

// ---------------- encoder: h0 = x @ W_atom + b_atom -> bf16 hi plane ---------
__global__ __launch_bounds__(256) void enc_atom(const float* __restrict__ X,
                                                const float* __restrict__ W,
                                                const float* __restrict__ b,
                                                short* __restrict__ Hhi) {
    __shared__ float as[32 * 48];
    int row0 = blockIdx.x * 32;
    int t = threadIdx.x;
    for (int i = t; i < 32 * 48; i += 256) {
        int r = i / 48, c = i - r * 48;
        int gr = row0 + r;
        as[i] = (gr < NNODES) ? X[gr * 48 + c] : 0.f;
    }
    __syncthreads();
    int c = t & 127, rh = t >> 7;
    float acc[16];
#pragma unroll
    for (int i = 0; i < 16; i++) acc[i] = 0.f;
    for (int k = 0; k < 48; k++) {
        float w = W[k * 128 + c];
#pragma unroll
        for (int i = 0; i < 16; i++) acc[i] += as[(rh * 16 + i) * 48 + k] * w;
    }
    float bb = b[c];
    for (int i = 0; i < 16; i++) {
        int gr = row0 + rh * 16 + i;
        if (gr < NNODES) Hhi[(size_t)gr * 128 + c] = f2bf(acc[i] + bb);
    }
}

// ---------------- eagg = S @ W_bond + b_bond * wsum  (K=11) ------------------
__global__ __launch_bounds__(256) void enc_bond(const float* __restrict__ S,
                                                const float* __restrict__ W,
                                                const float* __restrict__ b,
                                                const float* __restrict__ wsum,
                                                float* __restrict__ EA) {
    __shared__ float as[32 * 11];
    __shared__ float wss[32];
    int row0 = blockIdx.x * 32;
    int t = threadIdx.x;
    for (int i = t; i < 32 * 11; i += 256) {
        int r = i / 11, c = i - r * 11;
        int gr = row0 + r;
        as[i] = (gr < NNODES) ? S[gr * 11 + c] : 0.f;
    }
    if (t < 32) wss[t] = (row0 + t < NNODES) ? wsum[row0 + t] : 0.f;
    __syncthreads();
    int c = t & 127, rh = t >> 7;
    float acc[16];
#pragma unroll
    for (int i = 0; i < 16; i++) acc[i] = 0.f;
    for (int k = 0; k < 11; k++) {
        float w = W[k * 128 + c];
#pragma unroll
        for (int i = 0; i < 16; i++) acc[i] += as[(rh * 16 + i) * 11 + k] * w;
    }
    float bb = b[c];
    for (int i = 0; i < 16; i++) {
        int gr = row0 + rh * 16 + i;
        if (gr < NNODES) EA[gr * 128 + c] = acc[i] + bb * wss[rh * 16 + i];
    }
}

// ---------------- weight prep for 32x32x16 fragments (hi/lo planes) ----------
__global__ __launch_bounds__(256) void bprep(const float* __restrict__ Wl,
                                             const float* __restrict__ Wr,
                                             short* __restrict__ Bf) {
    int idx = blockIdx.x * 256 + threadIdx.x;
    if (idx >= NLAYERS * 32768) return;
    int layer = idx >> 15;
    int r = idx & 32767;
    int k = r >> 7, col = r & 127;
    float w = (k < 128) ? Wl[layer * 16384 + k * 128 + col]
                        : Wr[layer * 16384 + (k - 128) * 128 + col];
    short hi = f2bf(w);
    short lo = f2bf(w - bf2f(hi));
    int ks = k >> 4, half = (k >> 3) & 1, j = k & 7;
    int nt = col >> 5, n32 = col & 31;
    int fo = ((nt * 2 + half) * 32 + n32) * 8 + j;
    short* base = Bf + (size_t)layer * 65536 + ks * 4096;
    base[fo] = hi;
    base[2048 + fo] = lo;
}

// ---------------- fused: gather-agg -> LDS -> 32x32x16 MFMA GEMM + BN stats --
// 128 threads = 2 waves; block covers 64 rows. Wave tile 32 rows x 128 cols.
// Phase 1: 8 groups of 16 lanes aggregate rows into swizzled LDS bf16 tile.
// Phase 2: A(ks<8) from LDS, A(ks>=8)=own Hhi row; B hi/lo from global;
//          2 MFMAs per ntile (A hi-only). C stored bf16.
__global__ __launch_bounds__(128) void fused_layer(const short* __restrict__ Hhi,
                                                   const float* __restrict__ eagg,
                                                   const int* __restrict__ rowptr,
                                                   const int* __restrict__ epk,
                                                   const short* __restrict__ Bf,
                                                   const float* __restrict__ bias,
                                                   short* __restrict__ Cbf,
                                                   float* __restrict__ stat) {
    __shared__ short As[64 * 128];   // 16 KB, granule-swizzled
    __shared__ float s_s[128], s_q[128];
    int t = threadIdx.x;
    int row0 = blockIdx.x * 64;
    if (t < 128) { s_s[t] = 0.f; s_q[t] = 0.f; }

    // ---- Phase 1: gather-aggregate ----
    int l16 = t & 15;          // handles 8 cols: c8 = l16*8
    int ng = t >> 4;           // 8 groups
    for (int nb = ng; nb < 64; nb += 8) {
        int node = row0 + nb;
        float vf[8];
#pragma unroll
        for (int j = 0; j < 8; j++) vf[j] = 0.f;
        if (node < NNODES) {
            int b = rowptr[node], e = rowptr[node + 1];
            int p = b;
            for (; p + 1 < e; p += 2) {
                int2 pk0 = *(const int2*)(epk + (size_t)p * 8);
                int2 pk1 = *(const int2*)(epk + (size_t)(p + 1) * 8);
                float w0 = __int_as_float(pk0.y), w1 = __int_as_float(pk1.y);
                s16x8 h0 = *(const s16x8*)(Hhi + (size_t)pk0.x * 128 + l16 * 8);
                s16x8 h1 = *(const s16x8*)(Hhi + (size_t)pk1.x * 128 + l16 * 8);
#pragma unroll
                for (int j = 0; j < 8; j++)
                    vf[j] += bf2f(h0[j]) * w0 + bf2f(h1[j]) * w1;
            }
            if (p < e) {
                int2 pk0 = *(const int2*)(epk + (size_t)p * 8);
                float w0 = __int_as_float(pk0.y);
                s16x8 h0 = *(const s16x8*)(Hhi + (size_t)pk0.x * 128 + l16 * 8);
#pragma unroll
                for (int j = 0; j < 8; j++) vf[j] += bf2f(h0[j]) * w0;
            }
            float inv = 1.f / fmaxf((float)(e - b), 1.f);
            const float* ea = eagg + (size_t)node * 128 + l16 * 8;
            float4 e0 = *(const float4*)ea;
            float4 e1 = *(const float4*)(ea + 4);
            vf[0] = (vf[0] + e0.x) * inv; vf[1] = (vf[1] + e0.y) * inv;
            vf[2] = (vf[2] + e0.z) * inv; vf[3] = (vf[3] + e0.w) * inv;
            vf[4] = (vf[4] + e1.x) * inv; vf[5] = (vf[5] + e1.y) * inv;
            vf[6] = (vf[6] + e1.z) * inv; vf[7] = (vf[7] + e1.w) * inv;
        }
        s16x8 pk8;
#pragma unroll
        for (int j = 0; j < 8; j++) pk8[j] = f2bf(vf[j]);
        int gp = l16 ^ (nb & 15);
        *(s16x8*)&As[nb * 128 + gp * 8] = pk8;
    }
    __syncthreads();

    // ---- Phase 2: GEMM ----
    int wave = t >> 6, lane = t & 63;
    int n32 = lane & 31, half = lane >> 5;
    int wrow0 = row0 + wave * 32;
    int lr = wave * 32 + n32;              // block-local A row
    int myrow = row0 + lr;
    bool rowok = myrow < NNODES;
    size_t rbase = (size_t)myrow * 128;
    int acol = half * 8;

    f32x16 acc[4];
#pragma unroll
    for (int i = 0; i < 4; i++) acc[i] = (f32x16)(0.f);

    const short* bb0 = Bf + half * 256 + n32 * 8;
    int sw = lr & 15;

    s16x8 ah;
    s16x8 bh[4], bl[4];
    // prologue: kstep 0 from LDS
    ah = *(const s16x8*)&As[lr * 128 + ((0 * 2 + half) ^ sw) * 8];
#pragma unroll
    for (int nt = 0; nt < 4; nt++) {
        bh[nt] = *(const s16x8*)(bb0 + nt * 512);
        bl[nt] = *(const s16x8*)(bb0 + 2048 + nt * 512);
    }

#pragma unroll
    for (int ks = 0; ks < 16; ks++) {
        s16x8 ah2 = {0, 0, 0, 0, 0, 0, 0, 0};
        s16x8 bh2[4], bl2[4];
        if (ks < 15) {
            int kn = ks + 1;
            if (kn < 8) {
                ah2 = *(const s16x8*)&As[lr * 128 + ((kn * 2 + half) ^ sw) * 8];
            } else if (rowok) {
                ah2 = *(const s16x8*)(Hhi + rbase + (kn & 7) * 16 + acol);
            }
            const short* bbn = bb0 + kn * 4096;
#pragma unroll
            for (int nt = 0; nt < 4; nt++) {
                bh2[nt] = *(const s16x8*)(bbn + nt * 512);
                bl2[nt] = *(const s16x8*)(bbn + 2048 + nt * 512);
            }
        }
#pragma unroll
        for (int nt = 0; nt < 4; nt++) {
            acc[nt] = __builtin_amdgcn_mfma_f32_32x32x16_bf16(ah, bh[nt], acc[nt], 0, 0, 0);
            acc[nt] = __builtin_amdgcn_mfma_f32_32x32x16_bf16(ah, bl[nt], acc[nt], 0, 0, 0);
        }
        if (ks < 15) {
            ah = ah2;
#pragma unroll
            for (int nt = 0; nt < 4; nt++) {
                bh[nt] = bh2[nt];
                bl[nt] = bl2[nt];
            }
        }
    }

    // epilogue: bias, bf16 C write, fused BN partial stats
    // C/D layout: col = nt*32 + n32, row = wrow0 + (reg&3) + 8*(reg>>2) + 4*half
#pragma unroll
    for (int nt = 0; nt < 4; nt++) {
        int col = nt * 32 + n32;
        float bb = bias[col];
        float ss = 0.f, qq = 0.f;
#pragma unroll
        for (int reg = 0; reg < 16; reg++) {
            int r = wrow0 + (reg & 3) + 8 * (reg >> 2) + 4 * half;
            if (r < NNODES) {
                float v = acc[nt][reg] + bb;
                Cbf[(size_t)r * 128 + col] = f2bf(v);
                ss += v;
                qq += v * v;
            }
        }
        ss += __shfl_xor(ss, 32);
        qq += __shfl_xor(qq, 32);
        if (half == 0) {
            atomicAdd(&s_s[col], ss);
            atomicAdd(&s_q[col], qq);
        }
    }
    __syncthreads();
    if (t < 128) {
        atomicAdd(&stat[t], s_s[t]);
        atomicAdd(&stat[128 + t], s_q[t]);
    }
}

// ---------------- BN apply (+inline coef) + ReLU + xpool ---------------------
__global__ __launch_bounds__(256) void bn_apply(const short* __restrict__ Cbf,
                                                short* __restrict__ Hhi,
                                                float* __restrict__ Hf32,
                                                const float* __restrict__ stat,
                                                const float* __restrict__ gamma,
                                                const float* __restrict__ beta,
                                                const int* __restrict__ batch,
                                                float* __restrict__ pool,
                                                int layer, int relu) {
    __shared__ float csc[128], csh[128];
    int t = threadIdx.x;
    if (t < 128) {
        const float invM = 1.f / (float)NNODES;
        float mu = stat[t] * invM;
        float var = stat[128 + t] * invM - mu * mu;
        float inv = rsqrtf(var + BN_EPS);
        float sc = gamma[t] * inv;
        csc[t] = sc;
        csh[t] = beta[t] - mu * sc;
    }
    __syncthreads();
    int lane = t & 31, grp = t >> 5;
    int c4 = lane * 4;
    float4 sc = *(const float4*)&csc[c4];
    float4 sh = *(const float4*)&csh[c4];
    int row0 = blockIdx.x * 256;
    float4 accp = {0.f, 0.f, 0.f, 0.f};
    int curg = -1;
    float* pbase = pool + layer * 128 + c4;
    for (int rr = grp; rr < 256; rr += 8) {
        int r = row0 + rr;
        if (r >= NNODES) break;
        ushort4 cv = *(const ushort4*)&Cbf[(size_t)r * 128 + c4];
        float4 v;
        v.x = bf2f((short)cv.x) * sc.x + sh.x;
        v.y = bf2f((short)cv.y) * sc.y + sh.y;
        v.z = bf2f((short)cv.z) * sc.z + sh.z;
        v.w = bf2f((short)cv.w) * sc.w + sh.w;
        if (relu) {
            v.x = fmaxf(v.x, 0.f);
            v.y = fmaxf(v.y, 0.f);
            v.z = fmaxf(v.z, 0.f);
            v.w = fmaxf(v.w, 0.f);
        }
        if (Hf32) {
            *(float4*)&Hf32[(size_t)r * 128 + c4] = v;
        } else {
            ushort4 hv;
            hv.x = (unsigned short)f2bf(v.x);
            hv.y = (unsigned short)f2bf(v.y);
            hv.z = (unsigned short)f2bf(v.z);
            hv.w = (unsigned short)f2bf(v.w);
            *(ushort4*)&Hhi[(size_t)r * 128 + c4] = hv;
        }
        int g = batch[r];
        if (g != curg) {
            if (curg >= 0) {
                float* p = pbase + curg * 640;
                atomicAdd(p + 0, accp.x);
                atomicAdd(p + 1, accp.y);
                atomicAdd(p + 2, accp.z);
                atomicAdd(p + 3, accp.w);
            }
            curg = g;
            accp.x = accp.y = accp.z = accp.w = 0.f;
        }
        accp.x += v.x;
        accp.y += v.y;
        accp.z += v.z;
        accp.w += v.w;
    }
    if (curg >= 0) {
        float* p = pbase + curg * 640;
        atomicAdd(p + 0, accp.x);
        atomicAdd(p + 1, accp.y);
        atomicAdd(p + 2, accp.z);
        atomicAdd(p + 3, accp.w);
    }
}

extern "C" void kernel_launch(void* const* d_in, const int* in_sizes, int n_in,
                              void* d_out, int out_size, void* d_ws, size_t ws_size,
                              hipStream_t stream) {
    const int* batch = (const int*)d_in[0];
    const float* x = (const float*)d_in[1];
    const int* edge_index = (const int*)d_in[2];
    const float* edge_attr = (const float*)d_in[3];
    const float* edge_weight = (const float*)d_in[4];
    const float* W_atom = (const float*)d_in[5];
    const float* b_atom = (const float*)d_in[6];
    const float* W_bond = (const float*)d_in[7];
    const float* b_bond = (const float*)d_in[8];
    const float* Wl = (const float*)d_in[9];
    const float* bl = (const float*)d_in[10];
    const float* Wr = (const float*)d_in[11];
    const float* gamma = (const float*)d_in[12];
    const float* beta = (const float*)d_in[13];
    float* out = (float*)d_out;

    // ---- workspace layout ----
    char* ws = (char*)d_ws;
    size_t off = 0;
    auto alloc = [&](size_t bytes) -> void* {
        void* p = ws + off;
        off += (bytes + 255) & ~(size_t)255;
        return p;
    };
    short* Hhi = (short*)alloc((size_t)NNODES * 128 * 2);
    short* Cbf = (short*)alloc((size_t)NNODES * 128 * 2);
    float* eagg = (float*)alloc((size_t)NNODES * 128 * 4);
    int* epk = (int*)alloc((size_t)NEDGES * 32);
    int* rowptr = (int*)alloc((size_t)(NNODES + 1) * 4);
    int* cursor = (int*)alloc((size_t)NNODES * 4);
    int* deg = (int*)alloc((size_t)NNODES * 4);
    float* wsum = (float*)alloc((size_t)NNODES * 4);
    float* S = (float*)alloc((size_t)NNODES * 11 * 4);
    float* stat = (float*)alloc(NLAYERS * 256 * 4);
    int* local_excl = (int*)alloc((size_t)NNODES * 4);
    int* part = (int*)alloc(SCAN_BLOCKS * 4);
    int* blockoff = (int*)alloc(SCAN_BLOCKS * 4);
    short* Bf = (short*)alloc((size_t)NLAYERS * 65536 * 2);

    // ---- zero-init accumulation buffers ----
    hipMemsetAsync(out, 0, (size_t)NGRAPHS * 640 * 4, stream);
    hipMemsetAsync(deg, 0, (size_t)NNODES * 4, stream);
    hipMemsetAsync(stat, 0, NLAYERS * 256 * 4, stream);

    // ---- preprocessing ----
    deg_kernel<<<(NEDGES + 255) / 256, 256, 0, stream>>>(edge_index, deg);
    scan1<<<SCAN_BLOCKS, 256, 0, stream>>>(deg, local_excl, part);
    scan2<<<1, 256, 0, stream>>>(part, blockoff, rowptr);
    scan3<<<SCAN_BLOCKS, 256, 0, stream>>>(local_excl, blockoff, rowptr, cursor);
    edge_fill<<<(NEDGES + 255) / 256, 256, 0, stream>>>(edge_index, edge_weight,
                                                        edge_attr, cursor, epk);
    node_S<<<SCAN_BLOCKS, 256, 0, stream>>>(rowptr, epk, S, wsum);
    bprep<<<(NLAYERS * 32768 + 255) / 256, 256, 0, stream>>>(Wl, Wr, Bf);
    enc_atom<<<(NNODES + 31) / 32, 256, 0, stream>>>(x, W_atom, b_atom, Hhi);
    enc_bond<<<(NNODES + 31) / 32, 256, 0, stream>>>(S, W_bond, b_bond, wsum, eagg);

    // ---- layers ----
    for (int i = 0; i < NLAYERS; i++) {
        fused_layer<<<(NNODES + 63) / 64, 128, 0, stream>>>(Hhi, eagg, rowptr, epk,
                                                            Bf + (size_t)i * 65536,
                                                            bl + i * 128, Cbf,
                                                            stat + i * 256);
        int last = (i == NLAYERS - 1);
        bn_apply<<<(NNODES + 255) / 256, 256, 0, stream>>>(
            Cbf, Hhi, last ? (out + (size_t)NGRAPHS * 640) : nullptr,
            stat + i * 256, gamma + i * 128, beta + i * 128, batch, out, i,
            last ? 0 : 1);
    }
}

// Round 10
// 675.460 us; speedup vs baseline: 1.1916x; 1.1916x over previous
//
#include <hip/hip_runtime.h>
#include <hip/hip_bf16.h>

#define NNODES 50000
#define NEDGES 600000
#define NGRAPHS 128
#define EMB 128
#define NLAYERS 5
#define BN_EPS 1e-5f
#define SCAN_BLOCKS ((NNODES + 255) / 256)  // 196

typedef short s16x8 __attribute__((ext_vector_type(8)));
typedef float f32x16 __attribute__((ext_vector_type(16)));

__device__ __forceinline__ short f2bf(float f) {
    unsigned u = __builtin_bit_cast(unsigned, f);
    unsigned r = (u + 0x7fffu + ((u >> 16) & 1u)) >> 16;  // RNE
    return (short)r;
}
__device__ __forceinline__ float bf2f(short s) {
    return __builtin_bit_cast(float, ((unsigned)(unsigned short)s) << 16);
}

// ---------------- deg histogram (int atomics only) ---------------------------
__global__ __launch_bounds__(256) void deg_kernel(const int* __restrict__ ei,
                                                  int* __restrict__ deg) {
    int e = blockIdx.x * 256 + threadIdx.x;
    if (e >= NEDGES) return;
    atomicAdd(&deg[ei[NEDGES + e]], 1);
}

// ---------------- multi-block scan ------------------------------------------
__global__ __launch_bounds__(256) void scan1(const int* __restrict__ deg,
                                             int* __restrict__ local_excl,
                                             int* __restrict__ part) {
    __shared__ int sh[256];
    int t = threadIdx.x;
    int i = blockIdx.x * 256 + t;
    int v = (i < NNODES) ? deg[i] : 0;
    sh[t] = v;
    __syncthreads();
    for (int off = 1; off < 256; off <<= 1) {
        int u = (t >= off) ? sh[t - off] : 0;
        __syncthreads();
        sh[t] += u;
        __syncthreads();
    }
    if (i < NNODES) local_excl[i] = sh[t] - v;
    if (t == 255) part[blockIdx.x] = sh[255];
}

__global__ __launch_bounds__(256) void scan2(int* __restrict__ part,
                                             int* __restrict__ blockoff,
                                             int* __restrict__ rowptr) {
    __shared__ int sh[256];
    int t = threadIdx.x;
    int v = (t < SCAN_BLOCKS) ? part[t] : 0;
    sh[t] = v;
    __syncthreads();
    for (int off = 1; off < 256; off <<= 1) {
        int u = (t >= off) ? sh[t - off] : 0;
        __syncthreads();
        sh[t] += u;
        __syncthreads();
    }
    if (t < SCAN_BLOCKS) blockoff[t] = sh[t] - v;
    if (t == 255) rowptr[NNODES] = sh[255];
}

__global__ __launch_bounds__(256) void scan3(const int* __restrict__ local_excl,
                                             const int* __restrict__ blockoff,
                                             int* __restrict__ rowptr,
                                             int* __restrict__ cursor) {
    int i = blockIdx.x * 256 + threadIdx.x;
    if (i >= NNODES) return;
    int v = local_excl[i] + blockoff[blockIdx.x];
    rowptr[i] = v;
    cursor[i] = v;
}

// ---------------- fill CSR: 32B record {src, w, 11x bf16 attr, pad} ----------
__global__ __launch_bounds__(256) void edge_fill(const int* __restrict__ ei,
                                                 const float* __restrict__ ew,
                                                 const float* __restrict__ eattr,
                                                 int* __restrict__ cursor,
                                                 int* __restrict__ epk) {
    int e = blockIdx.x * 256 + threadIdx.x;
    if (e >= NEDGES) return;
    int src = ei[e];
    int dst = ei[NEDGES + e];
    int pos = atomicAdd(&cursor[dst], 1);
    int pk[8];
    pk[0] = src;
    pk[1] = __float_as_int(ew[e]);
    unsigned short a[12];
#pragma unroll
    for (int j = 0; j < 11; j++) a[j] = (unsigned short)f2bf(eattr[e * 11 + j]);
    a[11] = 0;
#pragma unroll
    for (int j = 0; j < 6; j++)
        pk[2 + j] = (int)a[2 * j] | ((int)a[2 * j + 1] << 16);
    int* dstp = epk + (size_t)pos * 8;
    *(int4*)dstp = *(int4*)pk;
    *(int4*)(dstp + 4) = *(int4*)(pk + 4);
}

// ---------------- S[n,11], wsum[n]: sequential CSR scan, thread-per-node -----
__global__ __launch_bounds__(256) void node_S(const int* __restrict__ rowptr,
                                              const int* __restrict__ epk,
                                              float* __restrict__ S,
                                              float* __restrict__ wsum) {
    int node = blockIdx.x * 256 + threadIdx.x;
    if (node >= NNODES) return;
    int b = rowptr[node], e = rowptr[node + 1];
    float s[11];
#pragma unroll
    for (int j = 0; j < 11; j++) s[j] = 0.f;
    float ws = 0.f;
    for (int p = b; p < e; p++) {
        const int* pk = epk + (size_t)p * 8;
        int4 lo = *(const int4*)pk;
        int4 hi = *(const int4*)(pk + 4);
        float w = __int_as_float(lo.y);
        ws += w;
        int packed[6] = {lo.z, lo.w, hi.x, hi.y, hi.z, hi.w};
#pragma unroll
        for (int j = 0; j < 11; j++) {
            short v = (short)((packed[j >> 1] >> ((j & 1) * 16)) & 0xffff);
            s[j] += bf2f(v) * w;
        }
    }
#pragma unroll
    for (int j = 0; j < 11; j++) S[node * 11 + j] = s[j];
    wsum[node] = ws;
}

// ---------------- encoder: h0 = x @ W_atom + b_atom -> bf16 hi plane ---------
__global__ __launch_bounds__(256) void enc_atom(const float* __restrict__ X,
                                                const float* __restrict__ W,
                                                const float* __restrict__ b,
                                                short* __restrict__ Hhi) {
    __shared__ float as[32 * 48];
    int row0 = blockIdx.x * 32;
    int t = threadIdx.x;
    for (int i = t; i < 32 * 48; i += 256) {
        int r = i / 48, c = i - r * 48;
        int gr = row0 + r;
        as[i] = (gr < NNODES) ? X[gr * 48 + c] : 0.f;
    }
    __syncthreads();
    int c = t & 127, rh = t >> 7;
    float acc[16];
#pragma unroll
    for (int i = 0; i < 16; i++) acc[i] = 0.f;
    for (int k = 0; k < 48; k++) {
        float w = W[k * 128 + c];
#pragma unroll
        for (int i = 0; i < 16; i++) acc[i] += as[(rh * 16 + i) * 48 + k] * w;
    }
    float bb = b[c];
    for (int i = 0; i < 16; i++) {
        int gr = row0 + rh * 16 + i;
        if (gr < NNODES) Hhi[(size_t)gr * 128 + c] = f2bf(acc[i] + bb);
    }
}

// ---------------- eagg = S @ W_bond + b_bond * wsum -> bf16 plane ------------
__global__ __launch_bounds__(256) void enc_bond(const float* __restrict__ S,
                                                const float* __restrict__ W,
                                                const float* __restrict__ b,
                                                const float* __restrict__ wsum,
                                                short* __restrict__ Ehi) {
    __shared__ float as[32 * 11];
    __shared__ float wss[32];
    int row0 = blockIdx.x * 32;
    int t = threadIdx.x;
    for (int i = t; i < 32 * 11; i += 256) {
        int r = i / 11, c = i - r * 11;
        int gr = row0 + r;
        as[i] = (gr < NNODES) ? S[gr * 11 + c] : 0.f;
    }
    if (t < 32) wss[t] = (row0 + t < NNODES) ? wsum[row0 + t] : 0.f;
    __syncthreads();
    int c = t & 127, rh = t >> 7;
    float acc[16];
#pragma unroll
    for (int i = 0; i < 16; i++) acc[i] = 0.f;
    for (int k = 0; k < 11; k++) {
        float w = W[k * 128 + c];
#pragma unroll
        for (int i = 0; i < 16; i++) acc[i] += as[(rh * 16 + i) * 11 + k] * w;
    }
    float bb = b[c];
    for (int i = 0; i < 16; i++) {
        int gr = row0 + rh * 16 + i;
        if (gr < NNODES) Ehi[(size_t)gr * 128 + c] = f2bf(acc[i] + bb * wss[rh * 16 + i]);
    }
}

// ---------------- per-layer aggregation: bf16 gather -> Ahi plane ------------
__global__ __launch_bounds__(256) void agg_kernel(const short* __restrict__ Hhi,
                                                  const short* __restrict__ Ehi,
                                                  const int* __restrict__ rowptr,
                                                  const int* __restrict__ epk,
                                                  short* __restrict__ Ahi) {
    int t = threadIdx.x;
    int lane = t & 31, grp = t >> 5;
    int c4 = lane * 4;
    int node = blockIdx.x * 8 + grp;
    if (node >= NNODES) return;
    int b = rowptr[node], e = rowptr[node + 1];
    float s0 = 0.f, s1 = 0.f, s2 = 0.f, s3 = 0.f;
    int p = b;
    for (; p + 1 < e; p += 2) {
        int2 pk0 = *(const int2*)(epk + (size_t)p * 8);
        int2 pk1 = *(const int2*)(epk + (size_t)(p + 1) * 8);
        float w0 = __int_as_float(pk0.y), w1 = __int_as_float(pk1.y);
        ushort4 h0 = *(const ushort4*)&Hhi[(size_t)pk0.x * 128 + c4];
        ushort4 h1 = *(const ushort4*)&Hhi[(size_t)pk1.x * 128 + c4];
        s0 += bf2f((short)h0.x) * w0 + bf2f((short)h1.x) * w1;
        s1 += bf2f((short)h0.y) * w0 + bf2f((short)h1.y) * w1;
        s2 += bf2f((short)h0.z) * w0 + bf2f((short)h1.z) * w1;
        s3 += bf2f((short)h0.w) * w0 + bf2f((short)h1.w) * w1;
    }
    if (p < e) {
        int2 pk0 = *(const int2*)(epk + (size_t)p * 8);
        float w0 = __int_as_float(pk0.y);
        ushort4 h0 = *(const ushort4*)&Hhi[(size_t)pk0.x * 128 + c4];
        s0 += bf2f((short)h0.x) * w0;
        s1 += bf2f((short)h0.y) * w0;
        s2 += bf2f((short)h0.z) * w0;
        s3 += bf2f((short)h0.w) * w0;
    }
    float inv = 1.f / fmaxf((float)(e - b), 1.f);
    ushort4 ea = *(const ushort4*)&Ehi[(size_t)node * 128 + c4];
    ushort4 o;
    o.x = (unsigned short)f2bf((s0 + bf2f((short)ea.x)) * inv);
    o.y = (unsigned short)f2bf((s1 + bf2f((short)ea.y)) * inv);
    o.z = (unsigned short)f2bf((s2 + bf2f((short)ea.z)) * inv);
    o.w = (unsigned short)f2bf((s3 + bf2f((short)ea.w)) * inv);
    *(ushort4*)&Ahi[(size_t)node * 128 + c4] = o;
}

// ---------------- weight prep for 32x32x16 fragments (hi/lo planes) ----------
__global__ __launch_bounds__(256) void bprep(const float* __restrict__ Wl,
                                             const float* __restrict__ Wr,
                                             short* __restrict__ Bf) {
    int idx = blockIdx.x * 256 + threadIdx.x;
    if (idx >= NLAYERS * 32768) return;
    int layer = idx >> 15;
    int r = idx & 32767;
    int k = r >> 7, col = r & 127;
    float w = (k < 128) ? Wl[layer * 16384 + k * 128 + col]
                        : Wr[layer * 16384 + (k - 128) * 128 + col];
    short hi = f2bf(w);
    short lo = f2bf(w - bf2f(hi));
    int ks = k >> 4, half = (k >> 3) & 1, j = k & 7;
    int nt = col >> 5, n32 = col & 31;
    int fo = ((nt * 2 + half) * 32 + n32) * 8 + j;
    short* base = Bf + (size_t)layer * 65536 + ks * 4096;
    base[fo] = hi;
    base[2048 + fo] = lo;
}

// ---------------- MFMA GEMM (32x32x16, A hi-only): C = [agg|h]@Bf + bias -----
// Wave tile 32 rows x 128 cols. Block = 4 waves = 128 rows. Register dbuf.
__global__ __launch_bounds__(256) void layer_gemm(const short* __restrict__ Ahi,
                                                  const short* __restrict__ Hhi,
                                                  const short* __restrict__ Bf,
                                                  const float* __restrict__ bias,
                                                  short* __restrict__ Cbf,
                                                  float* __restrict__ stat) {
    __shared__ float s_s[128], s_q[128];
    int t = threadIdx.x;
    int wave = t >> 6, lane = t & 63;
    int n32 = lane & 31, half = lane >> 5;
    int row0 = blockIdx.x * 128 + wave * 32;

    if (t < 128) { s_s[t] = 0.f; s_q[t] = 0.f; }
    __syncthreads();

    int myrow = row0 + n32;
    bool rowok = myrow < NNODES;
    size_t rbase = (size_t)myrow * 128;
    int acol = half * 8;

    f32x16 acc[4];
#pragma unroll
    for (int i = 0; i < 4; i++) acc[i] = (f32x16)(0.f);

    const short* bb0 = Bf + half * 256 + n32 * 8;

    s16x8 ah = {0, 0, 0, 0, 0, 0, 0, 0};
    s16x8 bh[4], bl[4];
    if (rowok) ah = *(const s16x8*)(Ahi + rbase + acol);
#pragma unroll
    for (int nt = 0; nt < 4; nt++) {
        bh[nt] = *(const s16x8*)(bb0 + nt * 512);
        bl[nt] = *(const s16x8*)(bb0 + 2048 + nt * 512);
    }

#pragma unroll
    for (int ks = 0; ks < 16; ks++) {
        s16x8 ah2 = {0, 0, 0, 0, 0, 0, 0, 0};
        s16x8 bh2[4], bl2[4];
        if (ks < 15) {
            int kn = ks + 1;
            if (rowok) {
                const short* hs = (kn < 8 ? Ahi : Hhi) + rbase + (kn & 7) * 16 + acol;
                ah2 = *(const s16x8*)hs;
            }
            const short* bbn = bb0 + kn * 4096;
#pragma unroll
            for (int nt = 0; nt < 4; nt++) {
                bh2[nt] = *(const s16x8*)(bbn + nt * 512);
                bl2[nt] = *(const s16x8*)(bbn + 2048 + nt * 512);
            }
        }
#pragma unroll
        for (int nt = 0; nt < 4; nt++) {
            acc[nt] = __builtin_amdgcn_mfma_f32_32x32x16_bf16(ah, bh[nt], acc[nt], 0, 0, 0);
            acc[nt] = __builtin_amdgcn_mfma_f32_32x32x16_bf16(ah, bl[nt], acc[nt], 0, 0, 0);
        }
        if (ks < 15) {
            ah = ah2;
#pragma unroll
            for (int nt = 0; nt < 4; nt++) {
                bh[nt] = bh2[nt];
                bl[nt] = bl2[nt];
            }
        }
    }

    // epilogue: bias, bf16 C write, fused BN partial stats
#pragma unroll
    for (int nt = 0; nt < 4; nt++) {
        int col = nt * 32 + n32;
        float bb = bias[col];
        float ss = 0.f, qq = 0.f;
#pragma unroll
        for (int reg = 0; reg < 16; reg++) {
            int r = row0 + (reg & 3) + 8 * (reg >> 2) + 4 * half;
            if (r < NNODES) {
                float v = acc[nt][reg] + bb;
                Cbf[(size_t)r * 128 + col] = f2bf(v);
                ss += v;
                qq += v * v;
            }
        }
        ss += __shfl_xor(ss, 32);
        qq += __shfl_xor(qq, 32);
        if (half == 0) {
            atomicAdd(&s_s[col], ss);
            atomicAdd(&s_q[col], qq);
        }
    }
    __syncthreads();
    if (t < 128) {
        atomicAdd(&stat[t], s_s[t]);
        atomicAdd(&stat[128 + t], s_q[t]);
    }
}

// ---------------- BN apply (+inline coef) + ReLU + xpool ---------------------
__global__ __launch_bounds__(256) void bn_apply(const short* __restrict__ Cbf,
                                                short* __restrict__ Hhi,
                                                float* __restrict__ Hf32,
                                                const float* __restrict__ stat,
                                                const float* __restrict__ gamma,
                                                const float* __restrict__ beta,
                                                const int* __restrict__ batch,
                                                float* __restrict__ pool,
                                                int layer, int relu) {
    __shared__ float csc[128], csh[128];
    int t = threadIdx.x;
    if (t < 128) {
        const float invM = 1.f / (float)NNODES;
        float mu = stat[t] * invM;
        float var = stat[128 + t] * invM - mu * mu;
        float inv = rsqrtf(var + BN_EPS);
        float sc = gamma[t] * inv;
        csc[t] = sc;
        csh[t] = beta[t] - mu * sc;
    }
    __syncthreads();
    int lane = t & 31, grp = t >> 5;
    int c4 = lane * 4;
    float4 sc = *(const float4*)&csc[c4];
    float4 sh = *(const float4*)&csh[c4];
    int row0 = blockIdx.x * 256;
    float4 accp = {0.f, 0.f, 0.f, 0.f};
    int curg = -1;
    float* pbase = pool + layer * 128 + c4;
    for (int rr = grp; rr < 256; rr += 8) {
        int r = row0 + rr;
        if (r >= NNODES) break;
        ushort4 cv = *(const ushort4*)&Cbf[(size_t)r * 128 + c4];
        float4 v;
        v.x = bf2f((short)cv.x) * sc.x + sh.x;
        v.y = bf2f((short)cv.y) * sc.y + sh.y;
        v.z = bf2f((short)cv.z) * sc.z + sh.z;
        v.w = bf2f((short)cv.w) * sc.w + sh.w;
        if (relu) {
            v.x = fmaxf(v.x, 0.f);
            v.y = fmaxf(v.y, 0.f);
            v.z = fmaxf(v.z, 0.f);
            v.w = fmaxf(v.w, 0.f);
        }
        if (Hf32) {
            *(float4*)&Hf32[(size_t)r * 128 + c4] = v;
        } else {
            ushort4 hv;
            hv.x = (unsigned short)f2bf(v.x);
            hv.y = (unsigned short)f2bf(v.y);
            hv.z = (unsigned short)f2bf(v.z);
            hv.w = (unsigned short)f2bf(v.w);
            *(ushort4*)&Hhi[(size_t)r * 128 + c4] = hv;
        }
        int g = batch[r];
        if (g != curg) {
            if (curg >= 0) {
                float* p = pbase + curg * 640;
                atomicAdd(p + 0, accp.x);
                atomicAdd(p + 1, accp.y);
                atomicAdd(p + 2, accp.z);
                atomicAdd(p + 3, accp.w);
            }
            curg = g;
            accp.x = accp.y = accp.z = accp.w = 0.f;
        }
        accp.x += v.x;
        accp.y += v.y;
        accp.z += v.z;
        accp.w += v.w;
    }
    if (curg >= 0) {
        float* p = pbase + curg * 640;
        atomicAdd(p + 0, accp.x);
        atomicAdd(p + 1, accp.y);
        atomicAdd(p + 2, accp.z);
        atomicAdd(p + 3, accp.w);
    }
}

extern "C" void kernel_launch(void* const* d_in, const int* in_sizes, int n_in,
                              void* d_out, int out_size, void* d_ws, size_t ws_size,
                              hipStream_t stream) {
    const int* batch = (const int*)d_in[0];
    const float* x = (const float*)d_in[1];
    const int* edge_index = (const int*)d_in[2];
    const float* edge_attr = (const float*)d_in[3];
    const float* edge_weight = (const float*)d_in[4];
    const float* W_atom = (const float*)d_in[5];
    const float* b_atom = (const float*)d_in[6];
    const float* W_bond = (const float*)d_in[7];
    const float* b_bond = (const float*)d_in[8];
    const float* Wl = (const float*)d_in[9];
    const float* bl = (const float*)d_in[10];
    const float* Wr = (const float*)d_in[11];
    const float* gamma = (const float*)d_in[12];
    const float* beta = (const float*)d_in[13];
    float* out = (float*)d_out;

    // ---- workspace layout ----
    char* ws = (char*)d_ws;
    size_t off = 0;
    auto alloc = [&](size_t bytes) -> void* {
        void* p = ws + off;
        off += (bytes + 255) & ~(size_t)255;
        return p;
    };
    short* Hhi = (short*)alloc((size_t)NNODES * 128 * 2);
    short* Ahi = (short*)alloc((size_t)NNODES * 128 * 2);
    short* Cbf = (short*)alloc((size_t)NNODES * 128 * 2);
    short* Ehi = (short*)alloc((size_t)NNODES * 128 * 2);
    int* epk = (int*)alloc((size_t)NEDGES * 32);
    int* rowptr = (int*)alloc((size_t)(NNODES + 1) * 4);
    int* cursor = (int*)alloc((size_t)NNODES * 4);
    int* deg = (int*)alloc((size_t)NNODES * 4);
    float* wsum = (float*)alloc((size_t)NNODES * 4);
    float* S = (float*)alloc((size_t)NNODES * 11 * 4);
    float* stat = (float*)alloc(NLAYERS * 256 * 4);
    int* local_excl = (int*)alloc((size_t)NNODES * 4);
    int* part = (int*)alloc(SCAN_BLOCKS * 4);
    int* blockoff = (int*)alloc(SCAN_BLOCKS * 4);
    short* Bf = (short*)alloc((size_t)NLAYERS * 65536 * 2);

    // ---- zero-init accumulation buffers ----
    hipMemsetAsync(out, 0, (size_t)NGRAPHS * 640 * 4, stream);
    hipMemsetAsync(deg, 0, (size_t)NNODES * 4, stream);
    hipMemsetAsync(stat, 0, NLAYERS * 256 * 4, stream);

    // ---- preprocessing ----
    deg_kernel<<<(NEDGES + 255) / 256, 256, 0, stream>>>(edge_index, deg);
    scan1<<<SCAN_BLOCKS, 256, 0, stream>>>(deg, local_excl, part);
    scan2<<<1, 256, 0, stream>>>(part, blockoff, rowptr);
    scan3<<<SCAN_BLOCKS, 256, 0, stream>>>(local_excl, blockoff, rowptr, cursor);
    edge_fill<<<(NEDGES + 255) / 256, 256, 0, stream>>>(edge_index, edge_weight,
                                                        edge_attr, cursor, epk);
    node_S<<<SCAN_BLOCKS, 256, 0, stream>>>(rowptr, epk, S, wsum);
    bprep<<<(NLAYERS * 32768 + 255) / 256, 256, 0, stream>>>(Wl, Wr, Bf);
    enc_atom<<<(NNODES + 31) / 32, 256, 0, stream>>>(x, W_atom, b_atom, Hhi);
    enc_bond<<<(NNODES + 31) / 32, 256, 0, stream>>>(S, W_bond, b_bond, wsum, Ehi);

    // ---- layers ----
    for (int i = 0; i < NLAYERS; i++) {
        agg_kernel<<<(NNODES + 7) / 8, 256, 0, stream>>>(Hhi, Ehi, rowptr, epk, Ahi);
        layer_gemm<<<(NNODES + 127) / 128, 256, 0, stream>>>(Ahi, Hhi,
                                                             Bf + (size_t)i * 65536,
                                                             bl + i * 128, Cbf,
                                                             stat + i * 256);
        int last = (i == NLAYERS - 1);
        bn_apply<<<(NNODES + 255) / 256, 256, 0, stream>>>(
            Cbf, Hhi, last ? (out + (size_t)NGRAPHS * 640) : nullptr,
            stat + i * 256, gamma + i * 128, beta + i * 128, batch, out, i,
            last ? 0 : 1);
    }
}